// Round 2
// baseline (272.670 us; speedup 1.0000x reference)
//
#include <hip/hip_runtime.h>
#include <hip/hip_bf16.h>
#include <stdint.h>

#define BB   8
#define NN   4096
#define FIN  32
#define FF   33          // FIN + 1 noise channel
#define KPAD 64          // pad feature dim to 2 MFMA k-steps
#define NQ   (BB*NN)     // 32768 query points
#define THR  27.0f       // d2 threshold: exp(-27)=1.9e-12; survivors/query ~ Poisson(4.6)
#define CAP  16
#define INF_IDX 0x7FFFFFFF

// workspace layout (bytes) — fast path, ~6.6 MB total
#define OFF_FB16   0ull
#define OFF_SQ     (OFF_FB16 + (size_t)NQ*KPAD*2)     // 4 MB
#define OFF_CNT    (OFF_SQ   + (size_t)NQ*4)
#define OFF_LISTS  (OFF_CNT  + (size_t)NQ*4)
#define OFF_PART   (OFF_LISTS + (size_t)NQ*CAP*4)     // +2 MB
#define WS_NEED    (OFF_PART + (size_t)(NQ/4)*4)

typedef short short8 __attribute__((ext_vector_type(8)));
typedef float floatx4 __attribute__((ext_vector_type(4)));

// ---------------- prep: f = [x, noise] -> bf16 padded rows + fp32 sq ----------------
__global__ __launch_bounds__(256) void prep_kernel(const float* __restrict__ x,
                                                   const float* __restrict__ noise,
                                                   unsigned short* __restrict__ fb,
                                                   float* __restrict__ sqv) {
    int q = blockIdx.x * 256 + threadIdx.x;
    if (q >= NQ) return;
    const float* xr = x + (size_t)q * FIN;
    float v[FF];
#pragma unroll
    for (int d = 0; d < FIN; ++d) v[d] = xr[d];
    v[FIN] = noise[q];
    float s = 0.f;
#pragma unroll
    for (int d = 0; d < FF; ++d) s += v[d] * v[d];
    sqv[q] = s;
    unsigned short row[KPAD];
#pragma unroll
    for (int d = 0; d < FF; ++d) {
        __hip_bfloat16 h = __float2bfloat16(v[d]);
        row[d] = *(unsigned short*)&h;
    }
#pragma unroll
    for (int d = FF; d < KPAD; ++d) row[d] = 0;
    uint4* dst = (uint4*)(fb + (size_t)q * KPAD);
    const uint4* src = (const uint4*)row;
#pragma unroll
    for (int i = 0; i < 8; ++i) dst[i] = src[i];
}

// ---------------- phase 1: MFMA score sieve -> survivor lists (self excluded) ----------------
// survive iff dot > 0.5*(sq_n + sq_m - THR)  <=>  d2 = sq_n + sq_m - 2*dot < THR
__global__ __launch_bounds__(256) void knn_kernel(const unsigned short* __restrict__ fb,
                                                  const float* __restrict__ sqv,
                                                  int* __restrict__ cnt,
                                                  int* __restrict__ lists) {
    int bb   = blockIdx.x >> 6;    // batch
    int qt   = blockIdx.x & 63;    // 64-row query tile within batch
    int wid  = threadIdx.x >> 6;
    int lane = threadIdx.x & 63;
    int qb   = qt * 64 + wid * 16; // wave's query base (within batch)
    int g16  = lane >> 4;          // k-group 0..3
    int l16  = lane & 15;
    size_t base = (size_t)bb * NN;

    const short8* fA = (const short8*)(fb + (base + qb + l16) * KPAD + g16 * 8);
    short8 a0 = fA[0];
    short8 a1 = fA[4];   // k += 32

    float t[4];
#pragma unroll
    for (int r = 0; r < 4; ++r)
        t[r] = 0.5f * sqv[base + qb + g16 * 4 + r] - (0.5f * THR);

    for (int mt = 0; mt < NN / 16; ++mt) {
        int mb = mt * 16;
        const short8* fBp = (const short8*)(fb + (base + mb + l16) * KPAD + g16 * 8);
        short8 b0 = fBp[0];
        short8 b1v = fBp[4];
        floatx4 acc = {0.f, 0.f, 0.f, 0.f};
        acc = __builtin_amdgcn_mfma_f32_16x16x32_bf16(a0, b0, acc, 0, 0, 0);
        acc = __builtin_amdgcn_mfma_f32_16x16x32_bf16(a1, b1v, acc, 0, 0, 0);
        float hc = 0.5f * sqv[base + mb + l16];   // C/D col = lane&15
        bool cc[4];
        cc[0] = acc[0] > t[0] + hc;
        cc[1] = acc[1] > t[1] + hc;
        cc[2] = acc[2] > t[2] + hc;
        cc[3] = acc[3] > t[3] + hc;
        if (cc[0] || cc[1] || cc[2] || cc[3]) {
#pragma unroll
            for (int r = 0; r < 4; ++r) {
                int n = qb + g16 * 4 + r;          // C/D row = (lane>>4)*4 + reg
                int m = mb + l16;
                if (cc[r] && n != m) {
                    int pos = atomicAdd(&cnt[base + n], 1);
                    if (pos < CAP) lists[(base + n) * CAP + pos] = m;
                }
            }
        }
    }
}

// ---------------- shared head: [f, md] @ W1 + b1, relu, out, mse partial ----------------
__device__ inline void head_epilogue(int wid, int lane, int q, float fnd, float md,
                                     const float* __restrict__ y,
                                     const float* __restrict__ W1,
                                     const float* __restrict__ b1,
                                     float* __restrict__ out,
                                     float* __restrict__ partials,
                                     float (*e_lds)[2 * FF], float* msep) {
    if (lane < FF) {
        e_lds[wid][lane]      = fnd;
        e_lds[wid][FF + lane] = md;
    }
    __syncthreads();
    float g = 0.f;
    if (lane < FIN) {
        g = b1[lane];
#pragma unroll
        for (int e = 0; e < 2 * FF; ++e)
            g = fmaf(e_lds[wid][e], W1[e * FIN + lane], g);
        g = fmaxf(g, 0.f);
        out[(size_t)q * FIN + lane] = g;
    }
    float d = 0.f;
    if (lane < FIN) {
        float t = g - y[(size_t)q * FIN + lane];
        d = t * t;
    }
#pragma unroll
    for (int off = 32; off; off >>= 1) d += __shfl_xor(d, off);
    if (lane == 0) msep[wid] = d;
    __syncthreads();
    if (threadIdx.x == 0)
        partials[blockIdx.x] = msep[0] + msep[1] + msep[2] + msep[3];
}

// ---------------- phase 2 (fast): exact fp32 weights over survivors; self explicit ----------------
__global__ __launch_bounds__(256) void gather_kernel(const float* __restrict__ x,
                                                     const float* __restrict__ noise,
                                                     const float* __restrict__ y,
                                                     const float* __restrict__ W1,
                                                     const float* __restrict__ b1,
                                                     const int* __restrict__ cnt,
                                                     const int* __restrict__ lists,
                                                     float* __restrict__ out,
                                                     float* __restrict__ partials) {
    __shared__ float e_lds[4][2 * FF];
    __shared__ float msep[4];
    int wid = threadIdx.x >> 6, lane = threadIdx.x & 63;
    int q = blockIdx.x * 4 + wid;
    int bb = q >> 12;
    int nloc = q & (NN - 1);
    size_t base = (size_t)bb * NN;

    float fnd = 0.f;
    if (lane < FIN)          fnd = x[(size_t)q * FIN + lane];
    else if (lane == FF - 1) fnd = noise[q];

    int c = cnt[q];
    if (c > CAP) c = CAP;
    int mj = (lane < c) ? lists[(size_t)q * CAP + lane] : INF_IDX;
    if (mj == nloc) mj = INF_IDX;   // self handled explicitly

    float den = 1.f, num = 0.f;     // self: w=1 (s==0 exactly), diff==0
    for (int it = 0; it < c; ++it) {
        int v = mj;                 // extract smallest remaining index (deterministic order)
#pragma unroll
        for (int off = 32; off; off >>= 1) {
            int o = __shfl_xor(v, off);
            v = v < o ? v : o;
        }
        if (v == INF_IDX) break;
        if (mj == v) mj = INF_IDX;
        int m = v;
        float fmd = 0.f;
        if (lane < FIN)          fmd = x[(base + m) * (size_t)FIN + lane];
        else if (lane == FF - 1) fmd = noise[base + m];
        float diff = (lane < FF) ? (fmd - fnd) : 0.f;
        float s = diff * diff;
#pragma unroll
        for (int off = 32; off; off >>= 1) s += __shfl_xor(s, off);
        float w = __expf(-s);       // exact fp32 d2: garbage survivors -> w ~ e^-60 ~ 0
        den += w;
        num += w * diff;
    }
    float md = num / den;           // den >= 1 always

    head_epilogue(wid, lane, q, fnd, md, y, W1, b1, out, partials, e_lds, msep);
}

// ---------------- phase 2 (fallback, ws too small): brute-force exact scan ----------------
__global__ __launch_bounds__(256) void gather_brute(const float* __restrict__ x,
                                                    const float* __restrict__ noise,
                                                    const float* __restrict__ y,
                                                    const float* __restrict__ W1,
                                                    const float* __restrict__ b1,
                                                    float* __restrict__ out,
                                                    float* __restrict__ partials) {
    __shared__ float e_lds[4][2 * FF];
    __shared__ float msep[4];
    int wid = threadIdx.x >> 6, lane = threadIdx.x & 63;
    int q = blockIdx.x * 4 + wid;
    int bb = q >> 12;
    int nloc = q & (NN - 1);
    size_t base = (size_t)bb * NN;

    float fnd = 0.f;
    if (lane < FIN)          fnd = x[(size_t)q * FIN + lane];
    else if (lane == FF - 1) fnd = noise[q];

    float den = 1.f, num = 0.f;
    for (int m = 0; m < NN; ++m) {
        if (m == nloc) continue;
        float fmd = 0.f;
        if (lane < FIN)          fmd = x[(base + m) * (size_t)FIN + lane];
        else if (lane == FF - 1) fmd = noise[base + m];
        float diff = (lane < FF) ? (fmd - fnd) : 0.f;
        float s = diff * diff;
#pragma unroll
        for (int off = 32; off; off >>= 1) s += __shfl_xor(s, off);
        float w = __expf(-s);
        den += w;
        num += w * diff;
    }
    float md = num / den;

    head_epilogue(wid, lane, q, fnd, md, y, W1, b1, out, partials, e_lds, msep);
}

// ---------------- final: gen_mse ----------------
__global__ __launch_bounds__(256) void reduce_kernel(const float* __restrict__ partials,
                                                     float* __restrict__ out) {
    __shared__ float s[256];
    float a = 0.f;
    for (int i = threadIdx.x; i < NQ / 4; i += 256) a += partials[i];
    s[threadIdx.x] = a;
    __syncthreads();
    for (int st = 128; st; st >>= 1) {
        if (threadIdx.x < st) s[threadIdx.x] += s[threadIdx.x + st];
        __syncthreads();
    }
    if (threadIdx.x == 0) out[(size_t)NQ * FIN] = s[0] / (float)((size_t)NQ * FIN);
}

extern "C" void kernel_launch(void* const* d_in, const int* in_sizes, int n_in,
                              void* d_out, int out_size, void* d_ws, size_t ws_size,
                              hipStream_t stream) {
    const float* x     = (const float*)d_in[0];
    const float* noise = (const float*)d_in[1];
    const float* y     = (const float*)d_in[2];
    const float* W1    = (const float*)d_in[3];
    const float* b1    = (const float*)d_in[4];
    float* out = (float*)d_out;
    char* ws = (char*)d_ws;

    if (ws_size >= WS_NEED) {
        unsigned short* fb = (unsigned short*)(ws + OFF_FB16);
        float* sqv     = (float*)(ws + OFF_SQ);
        int*   cnt     = (int*)(ws + OFF_CNT);
        int*   lists   = (int*)(ws + OFF_LISTS);
        float* partial = (float*)(ws + OFF_PART);

        hipMemsetAsync(cnt, 0, NQ * sizeof(int), stream);
        prep_kernel<<<NQ / 256, 256, 0, stream>>>(x, noise, fb, sqv);
        knn_kernel<<<BB * (NN / 64), 256, 0, stream>>>(fb, sqv, cnt, lists);
        gather_kernel<<<NQ / 4, 256, 0, stream>>>(x, noise, y, W1, b1, cnt, lists, out, partial);
        reduce_kernel<<<1, 256, 0, stream>>>(partial, out);
    } else {
        // brute-force exact path: needs only 32 KB of scratch for MSE partials
        float* partial = (float*)ws;
        gather_brute<<<NQ / 4, 256, 0, stream>>>(x, noise, y, W1, b1, out, partial);
        reduce_kernel<<<1, 256, 0, stream>>>(partial, out);
    }
}

// Round 3
// 139.931 us; speedup vs baseline: 1.9486x; 1.9486x over previous
//
#include <hip/hip_runtime.h>
#include <hip/hip_bf16.h>
#include <stdint.h>

#define BB   8
#define NN   4096
#define FIN  32
#define FF   33          // FIN + 1 noise channel
#define KPAD 64          // pad feature dim to 2 MFMA k-steps
#define NQ   (BB*NN)     // 32768 query points
#define THR  27.0f       // d2 threshold: exp(-27)=1.9e-12; survivors/query ~ Poisson(4.6)
#define CAP  16
#define MSPLIT 16        // m-range split for occupancy
#define INF_IDX 0x7FFFFFFF

// workspace layout (bytes) — fast path, ~6.6 MB total
#define OFF_FB16   0ull
#define OFF_SQ     (OFF_FB16 + (size_t)NQ*KPAD*2)     // 4 MB
#define OFF_CNT    (OFF_SQ   + (size_t)NQ*4)
#define OFF_LISTS  (OFF_CNT  + (size_t)NQ*4)
#define OFF_PART   (OFF_LISTS + (size_t)NQ*CAP*4)     // +2 MB
#define WS_NEED    (OFF_PART + (size_t)(NQ/4)*4)

typedef short short8 __attribute__((ext_vector_type(8)));
typedef float floatx4 __attribute__((ext_vector_type(4)));

// ---------------- prep: f = [x, noise] -> bf16 padded rows + fp32 sq ----------------
__global__ __launch_bounds__(256) void prep_kernel(const float* __restrict__ x,
                                                   const float* __restrict__ noise,
                                                   unsigned short* __restrict__ fb,
                                                   float* __restrict__ sqv) {
    int q = blockIdx.x * 256 + threadIdx.x;
    if (q >= NQ) return;
    const float* xr = x + (size_t)q * FIN;
    float v[FF];
#pragma unroll
    for (int d = 0; d < FIN; ++d) v[d] = xr[d];
    v[FIN] = noise[q];
    float s = 0.f;
#pragma unroll
    for (int d = 0; d < FF; ++d) s += v[d] * v[d];
    sqv[q] = s;
    unsigned short row[KPAD];
#pragma unroll
    for (int d = 0; d < FF; ++d) {
        __hip_bfloat16 h = __float2bfloat16(v[d]);
        row[d] = *(unsigned short*)&h;
    }
#pragma unroll
    for (int d = FF; d < KPAD; ++d) row[d] = 0;
    uint4* dst = (uint4*)(fb + (size_t)q * KPAD);
    const uint4* src = (const uint4*)row;
#pragma unroll
    for (int i = 0; i < 8; ++i) dst[i] = src[i];
}

// ---------------- phase 1: MFMA score sieve -> survivor lists (self excluded) ----------------
// survive iff dot > 0.5*(sq_n + sq_m - THR)  <=>  d2 = sq_n + sq_m - 2*dot < THR
// block = 256 thr (4 waves). wave owns 64 query rows (4 A-tiles of 16); block owns
// 256 query rows x a 256-column m-slab. grid = BB * (NN/256) * MSPLIT = 2048 blocks.
__global__ __launch_bounds__(256) void knn_kernel(const unsigned short* __restrict__ fb,
                                                  const float* __restrict__ sqv,
                                                  int* __restrict__ cnt,
                                                  int* __restrict__ lists) {
    int ms   = blockIdx.x & (MSPLIT - 1);
    int qt   = (blockIdx.x >> 4) & 15;
    int bb   = blockIdx.x >> 8;
    int wid  = threadIdx.x >> 6;
    int lane = threadIdx.x & 63;
    int qb   = qt * 256 + wid * 64;   // wave's query base (within batch)
    int g16  = lane >> 4;             // k-group 0..3
    int l16  = lane & 15;
    size_t base = (size_t)bb * NN;

    // A fragments for 4 query tiles (held across the whole m-slab)
    short8 a0[4], a1[4];
    float t[4][4];
#pragma unroll
    for (int a = 0; a < 4; ++a) {
        const short8* fA = (const short8*)(fb + (base + qb + a * 16 + l16) * KPAD + g16 * 8);
        a0[a] = fA[0];
        a1[a] = fA[4];   // k += 32
#pragma unroll
        for (int r = 0; r < 4; ++r)
            t[a][r] = 0.5f * sqv[base + qb + a * 16 + g16 * 4 + r] - (0.5f * THR);
    }

    int mstart = ms * (NN / MSPLIT);
    for (int mt = 0; mt < (NN / MSPLIT) / 16; ++mt) {
        int mb = mstart + mt * 16;
        const short8* fBp = (const short8*)(fb + (base + mb + l16) * KPAD + g16 * 8);
        short8 b0 = fBp[0];
        short8 b1v = fBp[4];
        float hc = 0.5f * sqv[base + mb + l16];   // C/D col = lane&15
#pragma unroll
        for (int a = 0; a < 4; ++a) {
            floatx4 acc = {0.f, 0.f, 0.f, 0.f};
            acc = __builtin_amdgcn_mfma_f32_16x16x32_bf16(a0[a], b0, acc, 0, 0, 0);
            acc = __builtin_amdgcn_mfma_f32_16x16x32_bf16(a1[a], b1v, acc, 0, 0, 0);
            bool cc[4];
            cc[0] = acc[0] > t[a][0] + hc;
            cc[1] = acc[1] > t[a][1] + hc;
            cc[2] = acc[2] > t[a][2] + hc;
            cc[3] = acc[3] > t[a][3] + hc;
            if (cc[0] || cc[1] || cc[2] || cc[3]) {
#pragma unroll
                for (int r = 0; r < 4; ++r) {
                    int n = qb + a * 16 + g16 * 4 + r;  // C/D row = (lane>>4)*4 + reg
                    int m = mb + l16;
                    if (cc[r] && n != m) {
                        int pos = atomicAdd(&cnt[base + n], 1);
                        if (pos < CAP) lists[(base + n) * CAP + pos] = m;
                    }
                }
            }
        }
    }
}

// ---------------- shared head: [f, md] @ W1 + b1, relu, out, mse partial ----------------
__device__ inline void head_epilogue(int wid, int lane, int q, float fnd, float md,
                                     const float* __restrict__ y,
                                     const float* __restrict__ W1,
                                     const float* __restrict__ b1,
                                     float* __restrict__ out,
                                     float* __restrict__ partials,
                                     float (*e_lds)[2 * FF], float* msep) {
    if (lane < FF) {
        e_lds[wid][lane]      = fnd;
        e_lds[wid][FF + lane] = md;
    }
    __syncthreads();
    float g = 0.f;
    if (lane < FIN) {
        g = b1[lane];
#pragma unroll
        for (int e = 0; e < 2 * FF; ++e)
            g = fmaf(e_lds[wid][e], W1[e * FIN + lane], g);
        g = fmaxf(g, 0.f);
        out[(size_t)q * FIN + lane] = g;
    }
    float d = 0.f;
    if (lane < FIN) {
        float t = g - y[(size_t)q * FIN + lane];
        d = t * t;
    }
#pragma unroll
    for (int off = 32; off; off >>= 1) d += __shfl_xor(d, off);
    if (lane == 0) msep[wid] = d;
    __syncthreads();
    if (threadIdx.x == 0)
        partials[blockIdx.x] = msep[0] + msep[1] + msep[2] + msep[3];
}

// ---------------- phase 2 (fast): exact fp32 weights over survivors; self explicit ----------------
__global__ __launch_bounds__(256) void gather_kernel(const float* __restrict__ x,
                                                     const float* __restrict__ noise,
                                                     const float* __restrict__ y,
                                                     const float* __restrict__ W1,
                                                     const float* __restrict__ b1,
                                                     const int* __restrict__ cnt,
                                                     const int* __restrict__ lists,
                                                     float* __restrict__ out,
                                                     float* __restrict__ partials) {
    __shared__ float e_lds[4][2 * FF];
    __shared__ float msep[4];
    int wid = threadIdx.x >> 6, lane = threadIdx.x & 63;
    int q = blockIdx.x * 4 + wid;
    int bb = q >> 12;
    int nloc = q & (NN - 1);
    size_t base = (size_t)bb * NN;

    float fnd = 0.f;
    if (lane < FIN)          fnd = x[(size_t)q * FIN + lane];
    else if (lane == FF - 1) fnd = noise[q];

    int c = cnt[q];
    if (c > CAP) c = CAP;
    int mj = (lane < c) ? lists[(size_t)q * CAP + lane] : INF_IDX;
    if (mj == nloc) mj = INF_IDX;   // self handled explicitly

    float den = 1.f, num = 0.f;     // self: w=1 (s==0 exactly), diff==0
    for (int it = 0; it < c; ++it) {
        int v = mj;                 // extract smallest remaining index (deterministic order)
#pragma unroll
        for (int off = 32; off; off >>= 1) {
            int o = __shfl_xor(v, off);
            v = v < o ? v : o;
        }
        if (v == INF_IDX) break;
        if (mj == v) mj = INF_IDX;
        int m = v;
        float fmd = 0.f;
        if (lane < FIN)          fmd = x[(base + m) * (size_t)FIN + lane];
        else if (lane == FF - 1) fmd = noise[base + m];
        float diff = (lane < FF) ? (fmd - fnd) : 0.f;
        float s = diff * diff;
#pragma unroll
        for (int off = 32; off; off >>= 1) s += __shfl_xor(s, off);
        float w = __expf(-s);       // exact fp32 d2: garbage survivors -> w ~ e^-60 ~ 0
        den += w;
        num += w * diff;
    }
    float md = num / den;           // den >= 1 always

    head_epilogue(wid, lane, q, fnd, md, y, W1, b1, out, partials, e_lds, msep);
}

// ---------------- phase 2 (fallback, ws too small): brute-force exact scan ----------------
__global__ __launch_bounds__(256) void gather_brute(const float* __restrict__ x,
                                                    const float* __restrict__ noise,
                                                    const float* __restrict__ y,
                                                    const float* __restrict__ W1,
                                                    const float* __restrict__ b1,
                                                    float* __restrict__ out,
                                                    float* __restrict__ partials) {
    __shared__ float e_lds[4][2 * FF];
    __shared__ float msep[4];
    int wid = threadIdx.x >> 6, lane = threadIdx.x & 63;
    int q = blockIdx.x * 4 + wid;
    int bb = q >> 12;
    int nloc = q & (NN - 1);
    size_t base = (size_t)bb * NN;

    float fnd = 0.f;
    if (lane < FIN)          fnd = x[(size_t)q * FIN + lane];
    else if (lane == FF - 1) fnd = noise[q];

    float den = 1.f, num = 0.f;
    for (int m = 0; m < NN; ++m) {
        if (m == nloc) continue;
        float fmd = 0.f;
        if (lane < FIN)          fmd = x[(base + m) * (size_t)FIN + lane];
        else if (lane == FF - 1) fmd = noise[base + m];
        float diff = (lane < FF) ? (fmd - fnd) : 0.f;
        float s = diff * diff;
#pragma unroll
        for (int off = 32; off; off >>= 1) s += __shfl_xor(s, off);
        float w = __expf(-s);
        den += w;
        num += w * diff;
    }
    float md = num / den;

    head_epilogue(wid, lane, q, fnd, md, y, W1, b1, out, partials, e_lds, msep);
}

// ---------------- final: gen_mse ----------------
__global__ __launch_bounds__(256) void reduce_kernel(const float* __restrict__ partials,
                                                     float* __restrict__ out) {
    __shared__ float s[256];
    float a = 0.f;
    for (int i = threadIdx.x; i < NQ / 4; i += 256) a += partials[i];
    s[threadIdx.x] = a;
    __syncthreads();
    for (int st = 128; st; st >>= 1) {
        if (threadIdx.x < st) s[threadIdx.x] += s[threadIdx.x + st];
        __syncthreads();
    }
    if (threadIdx.x == 0) out[(size_t)NQ * FIN] = s[0] / (float)((size_t)NQ * FIN);
}

extern "C" void kernel_launch(void* const* d_in, const int* in_sizes, int n_in,
                              void* d_out, int out_size, void* d_ws, size_t ws_size,
                              hipStream_t stream) {
    const float* x     = (const float*)d_in[0];
    const float* noise = (const float*)d_in[1];
    const float* y     = (const float*)d_in[2];
    const float* W1    = (const float*)d_in[3];
    const float* b1    = (const float*)d_in[4];
    float* out = (float*)d_out;
    char* ws = (char*)d_ws;

    if (ws_size >= WS_NEED) {
        unsigned short* fb = (unsigned short*)(ws + OFF_FB16);
        float* sqv     = (float*)(ws + OFF_SQ);
        int*   cnt     = (int*)(ws + OFF_CNT);
        int*   lists   = (int*)(ws + OFF_LISTS);
        float* partial = (float*)(ws + OFF_PART);

        hipMemsetAsync(cnt, 0, NQ * sizeof(int), stream);
        prep_kernel<<<NQ / 256, 256, 0, stream>>>(x, noise, fb, sqv);
        knn_kernel<<<BB * (NN / 256) * MSPLIT, 256, 0, stream>>>(fb, sqv, cnt, lists);
        gather_kernel<<<NQ / 4, 256, 0, stream>>>(x, noise, y, W1, b1, cnt, lists, out, partial);
        reduce_kernel<<<1, 256, 0, stream>>>(partial, out);
    } else {
        // brute-force exact path: needs only 32 KB of scratch for MSE partials
        float* partial = (float*)ws;
        gather_brute<<<NQ / 4, 256, 0, stream>>>(x, noise, y, W1, b1, out, partial);
        reduce_kernel<<<1, 256, 0, stream>>>(partial, out);
    }
}